// Round 17
// baseline (13912.772 us; speedup 1.0000x reference)
//
#include <hip/hip_runtime.h>
#include <math.h>

#define NB 64      // total batch
#define TT 512     // time steps
#define IN 128     // input dim
#define HD 512     // hidden dim
#define BGN 4      // batch groups
#define BGB 16     // batches per group
#define RBN 64     // row-blocks per batch group  (BGN*RBN = 256 blocks, 1/CU: LAW)

__device__ __forceinline__ float sigf(float x) { return 1.0f / (1.0f + expf(-x)); }
__device__ __forceinline__ float dot4(float4 a, float4 b) {
    return a.x*b.x + a.y*b.y + a.z*b.z + a.w*b.w;
}

// ---- device-coherent memory ops (bypass L1/L2 -> coherence point) ----
__device__ __forceinline__ void load_coh16(const float* p,
                                           float4& a, float4& b,
                                           float4& c, float4& d) {
    asm volatile(
        "global_load_dwordx4 %0, %4, off sc0 sc1\n\t"
        "global_load_dwordx4 %1, %4, off offset:16 sc0 sc1\n\t"
        "global_load_dwordx4 %2, %4, off offset:32 sc0 sc1\n\t"
        "global_load_dwordx4 %3, %4, off offset:48 sc0 sc1"
        : "=&v"(a), "=&v"(b), "=&v"(c), "=&v"(d)
        : "v"(p)
        : "memory");
}
__device__ __forceinline__ void wait_vm0() {
    asm volatile("s_waitcnt vmcnt(0)" ::: "memory");
}
__device__ __forceinline__ void store_coh(float* p, float v) {
    asm volatile("global_store_dword %0, %1, off sc0 sc1"
                 :: "v"(p), "v"(v) : "memory");
}
__device__ __forceinline__ int load_coh_int(const int* p) {
    int v;
    asm volatile("global_load_dword %0, %1, off sc0 sc1\n\ts_waitcnt vmcnt(0)"
                 : "=v"(v) : "v"(p) : "memory");
    return v;
}
__device__ __forceinline__ void store_coh_int(int* p, int v) {
    asm volatile("global_store_dword %0, %1, off sc0 sc1"
                 :: "v"(p), "v"(v) : "memory");
}

// 6-step butterfly over 64 lanes: on entry lane l holds partials A[j] (j=0..63,
// its k-slice's contribution to output j). On exit returns full sum for j = l.
__device__ __forceinline__ float wave_reduce64(float* A, int l) {
    #pragma unroll
    for (int s = 0; s < 6; ++s) {
        const int m = 1 << s;
        const bool bit = (l >> s) & 1;
        const int cnt = 64 >> (s + 1);
        #pragma unroll
        for (int i = 0; i < cnt; ++i) {
            float send = bit ? A[2*i]     : A[2*i + 1];
            float keep = bit ? A[2*i + 1] : A[2*i];
            float recv = __shfl_xor(send, m, 64);
            A[i] = keep + recv;
        }
    }
    return A[0];
}

// ws layout (floats): h0T[2][HD][NB] | h2T[2][HD][NB] | flags int[BGN][64]
// Pipeline step s: L0 computes h0_s from h0_{s-1}; L1 computes h2_{s-1} from
// h0_{s-1} and h2_{s-2}.  cur=s&1: read h0T[cur^1], h2T[cur]; write h0T[cur],
// h2T[cur^1]  (verified R0..R7/R13/R14 convention).
// COMPUTE BODY: R7/R13/R14 frozen b-loop (in-loop weight loads; hoisting spills:
// R5/R8/R12). GRID: 256 blocks = 1 block/CU ALWAYS (R10/R15: anything else
// risks non-co-residency -> stale-data answers).
// New this round: (1) ALL waves poll the slot flags (no wave0->sync wakeup);
// (2) x_lds staged at end of previous step, so the L0 x-part initializes A[64]
// in the shadow of the coherent h-loads (T14).
__global__ __launch_bounds__(512) void lstm_persist(
    const float* __restrict__ x,
    const float* __restrict__ Wih0, const float* __restrict__ Whh0,
    const float* __restrict__ bih0, const float* __restrict__ bhh0,
    const float* __restrict__ Wih1, const float* __restrict__ Whh1,
    const float* __restrict__ bih1, const float* __restrict__ bhh1,
    const float* __restrict__ fcW, const float* __restrict__ fcb,
    float* __restrict__ ws, float* __restrict__ out)
{
    __shared__ float x_lds[BGB][IN];    // 8 KB
    __shared__ float h0_lds[BGB][HD];   // 32 KB   [b][u'] transposed
    __shared__ float h2_lds[BGB][HD];   // 32 KB

    const int tid = threadIdx.x;
    const int l   = tid & 63;          // lane
    const int w   = tid >> 6;          // wave 0..7

    // ---- XCD-aware placement (T1, verified R7: FETCH 13.9GB -> 601MB) ----
    const int xcd  = blockIdx.x & 7;
    const int slot = blockIdx.x >> 3;        // 0..31 within XCD
    const int rb   = xcd * 8 + (slot >> 2);  // row-block 0..63
    const int bg   = slot & 3;               // batch group

    const int u   = rb * 8 + w;        // unit owned by this wave (both layers)
    const int us  = __builtin_amdgcn_readfirstlane(u);  // wave-uniform row base
    const int bg16 = bg * BGB;
    const int bl   = l & 15;           // state-batch lane

    float* h0T = ws;                       // [2][HD][NB]
    float* h2T = ws + 2 * HD * NB;         // [2][HD][NB]
    int*  flags  = (int*)(ws + 4 * HD * NB);
    int*  gslots = flags + bg * 64;        // this group's 64 slots

    // ---------------- prologue: bias setup (scalar-addressed) ----------------
    const float b0i = bih0[0*HD+us] + bhh0[0*HD+us];
    const float b0f = bih0[1*HD+us] + bhh0[1*HD+us];
    const float b0c = bih0[2*HD+us] + bhh0[2*HD+us];
    const float b0o = bih0[3*HD+us] + bhh0[3*HD+us];
    const float b1i = bih1[0*HD+us] + bhh1[0*HD+us];
    const float b1f = bih1[1*HD+us] + bhh1[1*HD+us];
    const float b1c = bih1[2*HD+us] + bhh1[2*HD+us];
    const float b1o = bih1[3*HD+us] + bhh1[3*HD+us];
    const float bias0 = (l & 32) ? ((l & 16) ? b0o : b0c) : ((l & 16) ? b0f : b0i);
    const float bias1 = (l & 32) ? ((l & 16) ? b1o : b1c) : ((l & 16) ? b1f : b1i);

    float c0r = 0.0f, c2r = 0.0f;      // cell state, valid on lanes 0..15

    const int xb = tid >> 5, xi = (tid & 31) * 4;
    // stage x for step 0 (barrier-independent; visible after first sync below)
    {
        float4 xp = *(const float4*)(x + ((size_t)(bg16 + xb) * TT + 0) * IN + xi);
        *(float4*)&x_lds[xb][xi] = xp;
    }

    for (int s = 0; s <= TT; ++s) {
        // ---- slot barrier: EVERY wave polls (lane j watches block j) ----
        if (s > 0) {
            const int* myslot = gslots + l;
            int spins = 0;
            while (!__all(load_coh_int(myslot) >= s)) {
                __builtin_amdgcn_s_sleep(2);
                if (++spins > (1 << 18)) break;   // bounded: bug -> wrong, not hang
            }
        }
        __syncthreads();   // #1: orders prev-step x_lds writes before reads

        const int cur = s & 1;
        const float* h0prev = h0T + (cur ^ 1) * HD * NB;  // h0_{s-1}
        const float* h2prev = h2T + cur * HD * NB;        // h2_{s-2}

        float A[64];

        // ---- issue coherent h loads; compute L0 x-part in their shadow ----
        {
            const float* s0 = h0prev + (size_t)tid * NB + bg16;
            const float* s2 = h2prev + (size_t)tid * NB + bg16;
            float4 q0, q1, q2, q3, p0, p1, p2, p3;
            load_coh16(s0, q0, q1, q2, q3);
            load_coh16(s2, p0, p1, p2, p3);

            if (s < TT) {
                // x-part: A[g*16+b] = Wih0[g-row, lane-slice] . x[b, lane-slice]
                float2 wx0 = *(const float2*)(Wih0 + ((size_t)0*HD+us) * IN + l*2);
                float2 wx1 = *(const float2*)(Wih0 + ((size_t)1*HD+us) * IN + l*2);
                float2 wx2 = *(const float2*)(Wih0 + ((size_t)2*HD+us) * IN + l*2);
                float2 wx3 = *(const float2*)(Wih0 + ((size_t)3*HD+us) * IN + l*2);
                #pragma unroll
                for (int b = 0; b < BGB; ++b) {
                    float2 xv = *(const float2*)&x_lds[b][l * 2];
                    A[ 0 + b] = wx0.x * xv.x + wx0.y * xv.y;
                    A[16 + b] = wx1.x * xv.x + wx1.y * xv.y;
                    A[32 + b] = wx2.x * xv.x + wx2.y * xv.y;
                    A[48 + b] = wx3.x * xv.x + wx3.y * xv.y;
                }
            }

            wait_vm0();
            h0_lds[ 0][tid]=q0.x; h0_lds[ 1][tid]=q0.y; h0_lds[ 2][tid]=q0.z; h0_lds[ 3][tid]=q0.w;
            h0_lds[ 4][tid]=q1.x; h0_lds[ 5][tid]=q1.y; h0_lds[ 6][tid]=q1.z; h0_lds[ 7][tid]=q1.w;
            h0_lds[ 8][tid]=q2.x; h0_lds[ 9][tid]=q2.y; h0_lds[10][tid]=q2.z; h0_lds[11][tid]=q2.w;
            h0_lds[12][tid]=q3.x; h0_lds[13][tid]=q3.y; h0_lds[14][tid]=q3.z; h0_lds[15][tid]=q3.w;
            h2_lds[ 0][tid]=p0.x; h2_lds[ 1][tid]=p0.y; h2_lds[ 2][tid]=p0.z; h2_lds[ 3][tid]=p0.w;
            h2_lds[ 4][tid]=p1.x; h2_lds[ 5][tid]=p1.y; h2_lds[ 6][tid]=p1.z; h2_lds[ 7][tid]=p1.w;
            h2_lds[ 8][tid]=p2.x; h2_lds[ 9][tid]=p2.y; h2_lds[10][tid]=p2.z; h2_lds[11][tid]=p2.w;
            h2_lds[12][tid]=p3.x; h2_lds[13][tid]=p3.y; h2_lds[14][tid]=p3.z; h2_lds[15][tid]=p3.w;
        }
        __syncthreads();   // #2: h staged

        float r0 = 0.0f, r1 = 0.0f;

        // ---- layer0: recurrent part (x-part already in A) — frozen b-loop ----
        if (s < TT) {
            #pragma unroll
            for (int b = 0; b < BGB; ++b) {
                float4 ha = *(const float4*)&h0_lds[b][l * 4];
                float4 hb = *(const float4*)&h0_lds[b][256 + l * 4];
                #pragma unroll
                for (int g = 0; g < 4; ++g) {
                    const size_t r = (size_t)g * HD + us;   // wave-uniform row
                    float4 wa = *(const float4*)(Whh0 + r * HD +       l * 4);
                    float4 wb = *(const float4*)(Whh0 + r * HD + 256 + l * 4);
                    A[g * 16 + b] += dot4(wa, ha) + dot4(wb, hb);
                }
            }
            r0 = wave_reduce64(A, l) + bias0;
        }
        // ---- layer1: gates for (unit us, all 16 batches) — frozen body ----
        if (s >= 1) {
            #pragma unroll
            for (int j = 0; j < 64; ++j) A[j] = 0.0f;
            #pragma unroll
            for (int b = 0; b < BGB; ++b) {
                float4 ha = *(const float4*)&h0_lds[b][l * 4];
                float4 hb = *(const float4*)&h0_lds[b][256 + l * 4];
                float4 qa = *(const float4*)&h2_lds[b][l * 4];
                float4 qb = *(const float4*)&h2_lds[b][256 + l * 4];
                #pragma unroll
                for (int g = 0; g < 4; ++g) {
                    const size_t r = (size_t)g * HD + us;   // wave-uniform row
                    float4 wi0 = *(const float4*)(Wih1 + r * HD +       l * 4);
                    float4 wi1 = *(const float4*)(Wih1 + r * HD + 256 + l * 4);
                    float4 wh0 = *(const float4*)(Whh1 + r * HD +       l * 4);
                    float4 wh1 = *(const float4*)(Whh1 + r * HD + 256 + l * 4);
                    A[g * 16 + b] += dot4(wi0, ha) + dot4(wi1, hb)
                                   + dot4(wh0, qa) + dot4(wh1, qb);
                }
            }
            r1 = wave_reduce64(A, l) + bias1;
        }

        // ---- gather gates to lanes 0..15 (shfl by ALL lanes), update state ----
        float gi0 = __shfl(r0, bl,      64);
        float gf0 = __shfl(r0, bl + 16, 64);
        float gc0 = __shfl(r0, bl + 32, 64);
        float go0 = __shfl(r0, bl + 48, 64);
        float gi1 = __shfl(r1, bl,      64);
        float gf1 = __shfl(r1, bl + 16, 64);
        float gc1 = __shfl(r1, bl + 32, 64);
        float go1 = __shfl(r1, bl + 48, 64);
        if (l < 16) {
            if (s < TT) {
                float cn = sigf(gf0) * c0r + sigf(gi0) * tanhf(gc0);
                c0r = cn;
                store_coh(h0T + cur * HD * NB + (size_t)us * NB + bg16 + bl,
                          sigf(go0) * tanhf(cn));
            }
            if (s >= 1) {
                float cn = sigf(gf1) * c2r + sigf(gi1) * tanhf(gc1);
                c2r = cn;
                store_coh(h2T + (cur ^ 1) * HD * NB + (size_t)us * NB + bg16 + bl,
                          sigf(go1) * tanhf(cn));   // h2_{s-1}
            }
        }

        // ---- arrive: #3 drains ALL waves' h stores, then slot store ----
        __syncthreads();
        if (tid == 0) store_coh_int(gslots + rb, s + 1);

        // ---- stage x for step s+1 (read at s+1 after sync #1) ----
        if (s + 1 < TT) {
            float4 xp = *(const float4*)(x + ((size_t)(bg16 + xb) * TT + (s + 1)) * IN + xi);
            *(float4*)&x_lds[xb][xi] = xp;
        }
    }

    // ---------------- FC tail: one block per batch group ----------------
    if (rb != 0) return;
    {
        if (tid < 64) {
            const int* myslot = gslots + l;
            int spins = 0;
            while (!__all(load_coh_int(myslot) >= TT + 1)) {
                __builtin_amdgcn_s_sleep(2);
                if (++spins > (1 << 18)) break;
            }
        }
        __syncthreads();

        // h2[TT-1] lives in buffer (TT-1)&1 = 1  (coherent reads)
        const float* hsrc = h2T + 1 * HD * NB + (size_t)tid * NB + bg16;
        float4 q0, q1, q2, q3;
        load_coh16(hsrc, q0, q1, q2, q3);
        wait_vm0();
        h2_lds[ 0][tid]=q0.x; h2_lds[ 1][tid]=q0.y; h2_lds[ 2][tid]=q0.z; h2_lds[ 3][tid]=q0.w;
        h2_lds[ 4][tid]=q1.x; h2_lds[ 5][tid]=q1.y; h2_lds[ 6][tid]=q1.z; h2_lds[ 7][tid]=q1.w;
        h2_lds[ 8][tid]=q2.x; h2_lds[ 9][tid]=q2.y; h2_lds[10][tid]=q2.z; h2_lds[11][tid]=q2.w;
        h2_lds[12][tid]=q3.x; h2_lds[13][tid]=q3.y; h2_lds[14][tid]=q3.z; h2_lds[15][tid]=q3.w;
        __syncthreads();

        const int bb = tid >> 5, oo = tid & 31;
        if (oo < 24) {
            float acc = fcb[oo];
            const float4* hrow = (const float4*)&h2_lds[bb][0];
            const float4* wrow = (const float4*)(fcW + (size_t)oo * HD);
            #pragma unroll 8
            for (int q = 0; q < HD / 4; ++q) acc += dot4(hrow[q], wrow[q]);
            out[(size_t)(bg16 + bb) * 24 + oo] = acc;
        }
    }
}

extern "C" void kernel_launch(void* const* d_in, const int* in_sizes, int n_in,
                              void* d_out, int out_size, void* d_ws, size_t ws_size,
                              hipStream_t stream)
{
    const float* x    = (const float*)d_in[0];
    const float* Wih0 = (const float*)d_in[1];
    const float* Whh0 = (const float*)d_in[2];
    const float* bih0 = (const float*)d_in[3];
    const float* bhh0 = (const float*)d_in[4];
    const float* Wih1 = (const float*)d_in[5];
    const float* Whh1 = (const float*)d_in[6];
    const float* bih1 = (const float*)d_in[7];
    const float* bhh1 = (const float*)d_in[8];
    const float* fcW  = (const float*)d_in[9];
    const float* fcb  = (const float*)d_in[10];

    // zero h ping-pong buffers + flag slots every call (graph-capture-safe)
    hipMemsetAsync(d_ws, 0, (size_t)(4 * HD * NB) * sizeof(float) + 1024, stream);

    lstm_persist<<<dim3(BGN * RBN), dim3(512), 0, stream>>>(
        x, Wih0, Whh0, bih0, bhh0, Wih1, Whh1, bih1, bhh1, fcW, fcb,
        (float*)d_ws, (float*)d_out);
}

// Round 18
// 7388.356 us; speedup vs baseline: 1.8831x; 1.8831x over previous
//
#include <hip/hip_runtime.h>
#include <math.h>

#define NB 64      // total batch
#define TT 512     // time steps
#define IN 128     // input dim
#define HD 512     // hidden dim
#define BGN 4      // batch groups
#define BGB 16     // batches per group
#define RBN 64     // row-blocks per batch group  (BGN*RBN = 256 blocks; <=256 ALWAYS)

__device__ __forceinline__ float sigf(float x) { return 1.0f / (1.0f + expf(-x)); }
__device__ __forceinline__ float dot4(float4 a, float4 b) {
    return a.x*b.x + a.y*b.y + a.z*b.z + a.w*b.w;
}

// ---- device-coherent memory ops (bypass L1/L2 -> coherence point) ----
__device__ __forceinline__ void load_coh16(const float* p,
                                           float4& a, float4& b,
                                           float4& c, float4& d) {
    asm volatile(
        "global_load_dwordx4 %0, %4, off sc0 sc1\n\t"
        "global_load_dwordx4 %1, %4, off offset:16 sc0 sc1\n\t"
        "global_load_dwordx4 %2, %4, off offset:32 sc0 sc1\n\t"
        "global_load_dwordx4 %3, %4, off offset:48 sc0 sc1"
        : "=&v"(a), "=&v"(b), "=&v"(c), "=&v"(d)
        : "v"(p)
        : "memory");
}
__device__ __forceinline__ void wait_vm0() {
    asm volatile("s_waitcnt vmcnt(0)" ::: "memory");
}
__device__ __forceinline__ void store_coh(float* p, float v) {
    asm volatile("global_store_dword %0, %1, off sc0 sc1"
                 :: "v"(p), "v"(v) : "memory");
}
__device__ __forceinline__ int load_coh_int(const int* p) {
    int v;
    asm volatile("global_load_dword %0, %1, off sc0 sc1\n\ts_waitcnt vmcnt(0)"
                 : "=v"(v) : "v"(p) : "memory");
    return v;
}
__device__ __forceinline__ void store_coh_int(int* p, int v) {
    asm volatile("global_store_dword %0, %1, off sc0 sc1"
                 :: "v"(p), "v"(v) : "memory");
}

// 6-step butterfly over 64 lanes: on entry lane l holds partials A[j] (j=0..63,
// its k-slice's contribution to output j). On exit returns full sum for j = l.
__device__ __forceinline__ float wave_reduce64(float* A, int l) {
    #pragma unroll
    for (int s = 0; s < 6; ++s) {
        const int m = 1 << s;
        const bool bit = (l >> s) & 1;
        const int cnt = 64 >> (s + 1);
        #pragma unroll
        for (int i = 0; i < cnt; ++i) {
            float send = bit ? A[2*i]     : A[2*i + 1];
            float keep = bit ? A[2*i + 1] : A[2*i];
            float recv = __shfl_xor(send, m, 64);
            A[i] = keep + recv;
        }
    }
    return A[0];
}

// ws layout (floats): h0T[2][HD][NB] | h2T[2][HD][NB] | flags int[BGN][64]
// Pipeline step s: L0 computes h0_s from h0_{s-1}; L1 computes h2_{s-1} from
// h0_{s-1} and h2_{s-2}.  cur=s&1: read h0T[cur^1], h2T[cur]; write h0T[cur],
// h2T[cur^1]  (verified Round-0..7/13/14 convention).
// COMPUTE BODY: frozen R7/R13/R14 equilibrium (in-loop weight loads, A[64],
// VGPR 108, zero spill). Five experiments (R5/R8/R12/R15/R16) prove any
// restructure that extends live ranges past this point spills through the
// 128-VGPR/512-thread cap. BARRIER: R13 slot-store protocol.
// GRID: 256 blocks = 1 block/CU ALWAYS (R10/R15 co-residency law).
__global__ __launch_bounds__(512) void lstm_persist(
    const float* __restrict__ x,
    const float* __restrict__ Wih0, const float* __restrict__ Whh0,
    const float* __restrict__ bih0, const float* __restrict__ bhh0,
    const float* __restrict__ Wih1, const float* __restrict__ Whh1,
    const float* __restrict__ bih1, const float* __restrict__ bhh1,
    const float* __restrict__ fcW, const float* __restrict__ fcb,
    float* __restrict__ ws, float* __restrict__ out)
{
    __shared__ float x_lds[BGB][IN];    // 8 KB
    __shared__ float h0_lds[BGB][HD];   // 32 KB   [b][u'] transposed
    __shared__ float h2_lds[BGB][HD];   // 32 KB

    const int tid = threadIdx.x;
    const int l   = tid & 63;          // lane
    const int w   = tid >> 6;          // wave 0..7

    // ---- XCD-aware placement (T1, verified R7: FETCH 13.9GB -> 601MB) ----
    const int xcd  = blockIdx.x & 7;
    const int slot = blockIdx.x >> 3;        // 0..31 within XCD
    const int rb   = xcd * 8 + (slot >> 2);  // row-block 0..63
    const int bg   = slot & 3;               // batch group

    const int u   = rb * 8 + w;        // unit owned by this wave (both layers)
    // provably wave-uniform copy: weight/bias addressing goes scalar (SGPR base)
    const int us  = __builtin_amdgcn_readfirstlane(u);
    const int bg16 = bg * BGB;
    const int bl   = l & 15;           // state-batch lane

    float* h0T = ws;                       // [2][HD][NB]
    float* h2T = ws + 2 * HD * NB;         // [2][HD][NB]
    int*  flags  = (int*)(ws + 4 * HD * NB);
    int*  gslots = flags + bg * 64;        // this group's 64 slots (256B, coalesced poll)

    // ---------------- prologue: bias setup (scalar-addressed) ----------------
    const float b0i = bih0[0*HD+us] + bhh0[0*HD+us];
    const float b0f = bih0[1*HD+us] + bhh0[1*HD+us];
    const float b0c = bih0[2*HD+us] + bhh0[2*HD+us];
    const float b0o = bih0[3*HD+us] + bhh0[3*HD+us];
    const float b1i = bih1[0*HD+us] + bhh1[0*HD+us];
    const float b1f = bih1[1*HD+us] + bhh1[1*HD+us];
    const float b1c = bih1[2*HD+us] + bhh1[2*HD+us];
    const float b1o = bih1[3*HD+us] + bhh1[3*HD+us];
    const float bias0 = (l & 32) ? ((l & 16) ? b0o : b0c) : ((l & 16) ? b0f : b0i);
    const float bias1 = (l & 32) ? ((l & 16) ? b1o : b1c) : ((l & 16) ? b1f : b1i);

    float c0r = 0.0f, c2r = 0.0f;      // cell state, valid on lanes 0..15

    for (int s = 0; s <= TT; ++s) {
        // ---- T14: issue x load for step s before the barrier (x is input) ----
        float4 xpf;
        const int xb = tid >> 5, xi = (tid & 31) * 4;
        if (s < TT)
            xpf = *(const float4*)(x + ((size_t)(bg16 + xb) * TT + s) * IN + xi);

        // ---- slot barrier: lane j of wave 0 watches block j of this group ----
        if (s > 0) {
            if (tid < 64) {
                const int* myslot = gslots + l;
                int spins = 0;
                while (!__all(load_coh_int(myslot) >= s)) {
                    __builtin_amdgcn_s_sleep(2);
                    if (++spins > (1 << 18)) break;   // bounded: bug -> wrong, not hang
                }
            }
            __syncthreads();   // release whole block; h reads below are coherent
        }

        const int cur = s & 1;
        const float* h0prev = h0T + (cur ^ 1) * HD * NB;  // h0_{s-1}
        const float* h2prev = h2T + cur * HD * NB;        // h2_{s-2}

        // ---- stage h0,h2 (coherent reads; transposed [b][u']) + x into LDS ----
        {
            const float* s0 = h0prev + (size_t)tid * NB + bg16;
            const float* s2 = h2prev + (size_t)tid * NB + bg16;
            float4 q0, q1, q2, q3, p0, p1, p2, p3;
            load_coh16(s0, q0, q1, q2, q3);
            load_coh16(s2, p0, p1, p2, p3);
            wait_vm0();
            h0_lds[ 0][tid]=q0.x; h0_lds[ 1][tid]=q0.y; h0_lds[ 2][tid]=q0.z; h0_lds[ 3][tid]=q0.w;
            h0_lds[ 4][tid]=q1.x; h0_lds[ 5][tid]=q1.y; h0_lds[ 6][tid]=q1.z; h0_lds[ 7][tid]=q1.w;
            h0_lds[ 8][tid]=q2.x; h0_lds[ 9][tid]=q2.y; h0_lds[10][tid]=q2.z; h0_lds[11][tid]=q2.w;
            h0_lds[12][tid]=q3.x; h0_lds[13][tid]=q3.y; h0_lds[14][tid]=q3.z; h0_lds[15][tid]=q3.w;
            h2_lds[ 0][tid]=p0.x; h2_lds[ 1][tid]=p0.y; h2_lds[ 2][tid]=p0.z; h2_lds[ 3][tid]=p0.w;
            h2_lds[ 4][tid]=p1.x; h2_lds[ 5][tid]=p1.y; h2_lds[ 6][tid]=p1.z; h2_lds[ 7][tid]=p1.w;
            h2_lds[ 8][tid]=p2.x; h2_lds[ 9][tid]=p2.y; h2_lds[10][tid]=p2.z; h2_lds[11][tid]=p2.w;
            h2_lds[12][tid]=p3.x; h2_lds[13][tid]=p3.y; h2_lds[14][tid]=p3.z; h2_lds[15][tid]=p3.w;
            if (s < TT)
                *(float4*)&x_lds[xb][xi] = xpf;
        }
        __syncthreads();

        float r0 = 0.0f, r1 = 0.0f;

        // ---- layer0: gates for (unit us, all 16 batches) — frozen body ----
        if (s < TT) {
            float A[64];
            #pragma unroll
            for (int j = 0; j < 64; ++j) A[j] = 0.0f;
            #pragma unroll
            for (int b = 0; b < BGB; ++b) {
                float4 ha = *(const float4*)&h0_lds[b][l * 4];
                float4 hb = *(const float4*)&h0_lds[b][256 + l * 4];
                float2 xv = *(const float2*)&x_lds[b][l * 2];
                #pragma unroll
                for (int g = 0; g < 4; ++g) {
                    const size_t r = (size_t)g * HD + us;   // wave-uniform row
                    float4 wa = *(const float4*)(Whh0 + r * HD +       l * 4);
                    float4 wb = *(const float4*)(Whh0 + r * HD + 256 + l * 4);
                    float2 wx = *(const float2*)(Wih0 + r * IN + l * 2);
                    A[g * 16 + b] += dot4(wa, ha) + dot4(wb, hb)
                                   + wx.x * xv.x + wx.y * xv.y;
                }
            }
            r0 = wave_reduce64(A, l) + bias0;
        }
        // ---- layer1: gates for (unit us, all 16 batches) — frozen body ----
        if (s >= 1) {
            float A[64];
            #pragma unroll
            for (int j = 0; j < 64; ++j) A[j] = 0.0f;
            #pragma unroll
            for (int b = 0; b < BGB; ++b) {
                float4 ha = *(const float4*)&h0_lds[b][l * 4];
                float4 hb = *(const float4*)&h0_lds[b][256 + l * 4];
                float4 qa = *(const float4*)&h2_lds[b][l * 4];
                float4 qb = *(const float4*)&h2_lds[b][256 + l * 4];
                #pragma unroll
                for (int g = 0; g < 4; ++g) {
                    const size_t r = (size_t)g * HD + us;   // wave-uniform row
                    float4 wi0 = *(const float4*)(Wih1 + r * HD +       l * 4);
                    float4 wi1 = *(const float4*)(Wih1 + r * HD + 256 + l * 4);
                    float4 wh0 = *(const float4*)(Whh1 + r * HD +       l * 4);
                    float4 wh1 = *(const float4*)(Whh1 + r * HD + 256 + l * 4);
                    A[g * 16 + b] += dot4(wi0, ha) + dot4(wi1, hb)
                                   + dot4(wh0, qa) + dot4(wh1, qb);
                }
            }
            r1 = wave_reduce64(A, l) + bias1;
        }

        // ---- gather gates to lanes 0..15 (shfl by ALL lanes), update state ----
        float gi0 = __shfl(r0, bl,      64);
        float gf0 = __shfl(r0, bl + 16, 64);
        float gc0 = __shfl(r0, bl + 32, 64);
        float go0 = __shfl(r0, bl + 48, 64);
        float gi1 = __shfl(r1, bl,      64);
        float gf1 = __shfl(r1, bl + 16, 64);
        float gc1 = __shfl(r1, bl + 32, 64);
        float go1 = __shfl(r1, bl + 48, 64);
        if (l < 16) {
            if (s < TT) {
                float cn = sigf(gf0) * c0r + sigf(gi0) * tanhf(gc0);
                c0r = cn;
                store_coh(h0T + cur * HD * NB + (size_t)us * NB + bg16 + bl,
                          sigf(go0) * tanhf(cn));
            }
            if (s >= 1) {
                float cn = sigf(gf1) * c2r + sigf(gi1) * tanhf(gc1);
                c2r = cn;
                store_coh(h2T + (cur ^ 1) * HD * NB + (size_t)us * NB + bg16 + bl,
                          sigf(go1) * tanhf(cn));   // h2_{s-1}
            }
        }

        // ---- arrive: barrier drains ALL waves' h stores (vmcnt0 each), then
        //      one independent slot store (no RMW convoy) ----
        __syncthreads();
        if (tid == 0) store_coh_int(gslots + rb, s + 1);
    }

    // ---------------- FC tail: one block per batch group ----------------
    if (rb != 0) return;
    {
        if (tid < 64) {
            const int* myslot = gslots + l;
            int spins = 0;
            while (!__all(load_coh_int(myslot) >= TT + 1)) {
                __builtin_amdgcn_s_sleep(2);
                if (++spins > (1 << 18)) break;
            }
        }
        __syncthreads();

        // h2[TT-1] lives in buffer (TT-1)&1 = 1  (coherent reads)
        const float* hsrc = h2T + 1 * HD * NB + (size_t)tid * NB + bg16;
        float4 q0, q1, q2, q3;
        load_coh16(hsrc, q0, q1, q2, q3);
        wait_vm0();
        h2_lds[ 0][tid]=q0.x; h2_lds[ 1][tid]=q0.y; h2_lds[ 2][tid]=q0.z; h2_lds[ 3][tid]=q0.w;
        h2_lds[ 4][tid]=q1.x; h2_lds[ 5][tid]=q1.y; h2_lds[ 6][tid]=q1.z; h2_lds[ 7][tid]=q1.w;
        h2_lds[ 8][tid]=q2.x; h2_lds[ 9][tid]=q2.y; h2_lds[10][tid]=q2.z; h2_lds[11][tid]=q2.w;
        h2_lds[12][tid]=q3.x; h2_lds[13][tid]=q3.y; h2_lds[14][tid]=q3.z; h2_lds[15][tid]=q3.w;
        __syncthreads();

        const int bb = tid >> 5, oo = tid & 31;
        if (oo < 24) {
            float acc = fcb[oo];
            const float4* hrow = (const float4*)&h2_lds[bb][0];
            const float4* wrow = (const float4*)(fcW + (size_t)oo * HD);
            #pragma unroll 8
            for (int q = 0; q < HD / 4; ++q) acc += dot4(hrow[q], wrow[q]);
            out[(size_t)(bg16 + bb) * 24 + oo] = acc;
        }
    }
}

extern "C" void kernel_launch(void* const* d_in, const int* in_sizes, int n_in,
                              void* d_out, int out_size, void* d_ws, size_t ws_size,
                              hipStream_t stream)
{
    const float* x    = (const float*)d_in[0];
    const float* Wih0 = (const float*)d_in[1];
    const float* Whh0 = (const float*)d_in[2];
    const float* bih0 = (const float*)d_in[3];
    const float* bhh0 = (const float*)d_in[4];
    const float* Wih1 = (const float*)d_in[5];
    const float* Whh1 = (const float*)d_in[6];
    const float* bih1 = (const float*)d_in[7];
    const float* bhh1 = (const float*)d_in[8];
    const float* fcW  = (const float*)d_in[9];
    const float* fcb  = (const float*)d_in[10];

    // zero h ping-pong buffers + flag slots every call (graph-capture-safe)
    hipMemsetAsync(d_ws, 0, (size_t)(4 * HD * NB) * sizeof(float) + 1024, stream);

    lstm_persist<<<dim3(BGN * RBN), dim3(512), 0, stream>>>(
        x, Wih0, Whh0, bih0, bhh0, Wih1, Whh1, bih1, bhh1, fcW, fcb,
        (float*)d_ws, (float*)d_out);
}

// Round 19
// 7193.488 us; speedup vs baseline: 1.9341x; 1.0271x over previous
//
#include <hip/hip_runtime.h>
#include <math.h>

#define NB 64      // total batch
#define TT 512     // time steps
#define IN 128     // input dim
#define HD 512     // hidden dim
#define BGN 4      // batch groups
#define BGB 16     // batches per group
#define RBN 64     // row-blocks per batch group  (BGN*RBN = 256 blocks; <=256 ALWAYS)

__device__ __forceinline__ float sigf(float x) { return 1.0f / (1.0f + expf(-x)); }
__device__ __forceinline__ float dot4(float4 a, float4 b) {
    return a.x*b.x + a.y*b.y + a.z*b.z + a.w*b.w;
}

// ---- device-coherent memory ops (bypass L1/L2 -> coherence point) ----
__device__ __forceinline__ void load_coh16(const float* p,
                                           float4& a, float4& b,
                                           float4& c, float4& d) {
    asm volatile(
        "global_load_dwordx4 %0, %4, off sc0 sc1\n\t"
        "global_load_dwordx4 %1, %4, off offset:16 sc0 sc1\n\t"
        "global_load_dwordx4 %2, %4, off offset:32 sc0 sc1\n\t"
        "global_load_dwordx4 %3, %4, off offset:48 sc0 sc1"
        : "=&v"(a), "=&v"(b), "=&v"(c), "=&v"(d)
        : "v"(p)
        : "memory");
}
__device__ __forceinline__ void wait_vm0() {
    asm volatile("s_waitcnt vmcnt(0)" ::: "memory");
}
__device__ __forceinline__ void store_coh(float* p, float v) {
    asm volatile("global_store_dword %0, %1, off sc0 sc1"
                 :: "v"(p), "v"(v) : "memory");
}
__device__ __forceinline__ int load_coh_int(const int* p) {
    int v;
    asm volatile("global_load_dword %0, %1, off sc0 sc1\n\ts_waitcnt vmcnt(0)"
                 : "=v"(v) : "v"(p) : "memory");
    return v;
}
__device__ __forceinline__ void store_coh_int(int* p, int v) {
    asm volatile("global_store_dword %0, %1, off sc0 sc1"
                 :: "v"(p), "v"(v) : "memory");
}

// 6-step butterfly over 64 lanes: on entry lane l holds partials A[j] (j=0..63,
// its k-slice's contribution to output j). On exit returns full sum for j = l.
__device__ __forceinline__ float wave_reduce64(float* A, int l) {
    #pragma unroll
    for (int s = 0; s < 6; ++s) {
        const int m = 1 << s;
        const bool bit = (l >> s) & 1;
        const int cnt = 64 >> (s + 1);
        #pragma unroll
        for (int i = 0; i < cnt; ++i) {
            float send = bit ? A[2*i]     : A[2*i + 1];
            float keep = bit ? A[2*i + 1] : A[2*i];
            float recv = __shfl_xor(send, m, 64);
            A[i] = keep + recv;
        }
    }
    return A[0];
}

// ws layout (floats): h0T[2][HD][NB] | h2T[2][HD][NB] | flags int[BGN][64]
// Pipeline step s: L0 computes h0_s from h0_{s-1}; L1 computes h2_{s-1} from
// h0_{s-1} and h2_{s-2}.  cur=s&1: read h0T[cur^1], h2T[cur]; write h0T[cur],
// h2T[cur^1]  (verified Round-0..7/13/14/17 convention).
// COMPUTE BODY: R14 equilibrium (in-loop weight loads, A[64], VGPR 108) with
// ONE change: batch-PAIR processing — each weight float4 loaded once feeds 2
// batches. Weight-load insts 448->224/wave/step; L2 stream 3.58->1.79 MB/
// block/step. Pressure est ~120-127 < 128 cap; WRITE_SIZE is the tripwire.
// BARRIER: R13 slot-store protocol. GRID: 256 blocks = 1 block/CU (LAW).
__global__ __launch_bounds__(512) void lstm_persist(
    const float* __restrict__ x,
    const float* __restrict__ Wih0, const float* __restrict__ Whh0,
    const float* __restrict__ bih0, const float* __restrict__ bhh0,
    const float* __restrict__ Wih1, const float* __restrict__ Whh1,
    const float* __restrict__ bih1, const float* __restrict__ bhh1,
    const float* __restrict__ fcW, const float* __restrict__ fcb,
    float* __restrict__ ws, float* __restrict__ out)
{
    __shared__ float x_lds[BGB][IN];    // 8 KB
    __shared__ float h0_lds[BGB][HD];   // 32 KB   [b][u'] transposed
    __shared__ float h2_lds[BGB][HD];   // 32 KB

    const int tid = threadIdx.x;
    const int l   = tid & 63;          // lane
    const int w   = tid >> 6;          // wave 0..7

    // ---- XCD-aware placement (T1, verified R7: FETCH 13.9GB -> 601MB) ----
    const int xcd  = blockIdx.x & 7;
    const int slot = blockIdx.x >> 3;        // 0..31 within XCD
    const int rb   = xcd * 8 + (slot >> 2);  // row-block 0..63
    const int bg   = slot & 3;               // batch group

    const int u   = rb * 8 + w;        // unit owned by this wave (both layers)
    const int us  = __builtin_amdgcn_readfirstlane(u);  // wave-uniform row base
    const int bg16 = bg * BGB;
    const int bl   = l & 15;           // state-batch lane

    float* h0T = ws;                       // [2][HD][NB]
    float* h2T = ws + 2 * HD * NB;         // [2][HD][NB]
    int*  flags  = (int*)(ws + 4 * HD * NB);
    int*  gslots = flags + bg * 64;        // this group's 64 slots (256B, coalesced poll)

    // ---------------- prologue: bias setup (scalar-addressed) ----------------
    const float b0i = bih0[0*HD+us] + bhh0[0*HD+us];
    const float b0f = bih0[1*HD+us] + bhh0[1*HD+us];
    const float b0c = bih0[2*HD+us] + bhh0[2*HD+us];
    const float b0o = bih0[3*HD+us] + bhh0[3*HD+us];
    const float b1i = bih1[0*HD+us] + bhh1[0*HD+us];
    const float b1f = bih1[1*HD+us] + bhh1[1*HD+us];
    const float b1c = bih1[2*HD+us] + bhh1[2*HD+us];
    const float b1o = bih1[3*HD+us] + bhh1[3*HD+us];
    const float bias0 = (l & 32) ? ((l & 16) ? b0o : b0c) : ((l & 16) ? b0f : b0i);
    const float bias1 = (l & 32) ? ((l & 16) ? b1o : b1c) : ((l & 16) ? b1f : b1i);

    float c0r = 0.0f, c2r = 0.0f;      // cell state, valid on lanes 0..15

    for (int s = 0; s <= TT; ++s) {
        // ---- T14: issue x load for step s before the barrier (x is input) ----
        float4 xpf;
        const int xb = tid >> 5, xi = (tid & 31) * 4;
        if (s < TT)
            xpf = *(const float4*)(x + ((size_t)(bg16 + xb) * TT + s) * IN + xi);

        // ---- slot barrier: lane j of wave 0 watches block j of this group ----
        if (s > 0) {
            if (tid < 64) {
                const int* myslot = gslots + l;
                int spins = 0;
                while (!__all(load_coh_int(myslot) >= s)) {
                    __builtin_amdgcn_s_sleep(2);
                    if (++spins > (1 << 18)) break;   // bounded: bug -> wrong, not hang
                }
            }
            __syncthreads();   // release whole block; h reads below are coherent
        }

        const int cur = s & 1;
        const float* h0prev = h0T + (cur ^ 1) * HD * NB;  // h0_{s-1}
        const float* h2prev = h2T + cur * HD * NB;        // h2_{s-2}

        // ---- stage h0,h2 (coherent reads; transposed [b][u']) + x into LDS ----
        {
            const float* s0 = h0prev + (size_t)tid * NB + bg16;
            const float* s2 = h2prev + (size_t)tid * NB + bg16;
            float4 q0, q1, q2, q3, p0, p1, p2, p3;
            load_coh16(s0, q0, q1, q2, q3);
            load_coh16(s2, p0, p1, p2, p3);
            wait_vm0();
            h0_lds[ 0][tid]=q0.x; h0_lds[ 1][tid]=q0.y; h0_lds[ 2][tid]=q0.z; h0_lds[ 3][tid]=q0.w;
            h0_lds[ 4][tid]=q1.x; h0_lds[ 5][tid]=q1.y; h0_lds[ 6][tid]=q1.z; h0_lds[ 7][tid]=q1.w;
            h0_lds[ 8][tid]=q2.x; h0_lds[ 9][tid]=q2.y; h0_lds[10][tid]=q2.z; h0_lds[11][tid]=q2.w;
            h0_lds[12][tid]=q3.x; h0_lds[13][tid]=q3.y; h0_lds[14][tid]=q3.z; h0_lds[15][tid]=q3.w;
            h2_lds[ 0][tid]=p0.x; h2_lds[ 1][tid]=p0.y; h2_lds[ 2][tid]=p0.z; h2_lds[ 3][tid]=p0.w;
            h2_lds[ 4][tid]=p1.x; h2_lds[ 5][tid]=p1.y; h2_lds[ 6][tid]=p1.z; h2_lds[ 7][tid]=p1.w;
            h2_lds[ 8][tid]=p2.x; h2_lds[ 9][tid]=p2.y; h2_lds[10][tid]=p2.z; h2_lds[11][tid]=p2.w;
            h2_lds[12][tid]=p3.x; h2_lds[13][tid]=p3.y; h2_lds[14][tid]=p3.z; h2_lds[15][tid]=p3.w;
            if (s < TT)
                *(float4*)&x_lds[xb][xi] = xpf;
        }
        __syncthreads();

        float r0 = 0.0f, r1 = 0.0f;

        // ---- layer0: batch-PAIR loop — each weight load feeds 2 batches ----
        if (s < TT) {
            float A[64];
            #pragma unroll
            for (int j = 0; j < 64; ++j) A[j] = 0.0f;
            #pragma unroll
            for (int bp = 0; bp < BGB / 2; ++bp) {
                const int b0 = bp * 2, b1 = bp * 2 + 1;
                float4 ha0 = *(const float4*)&h0_lds[b0][l * 4];
                float4 hb0 = *(const float4*)&h0_lds[b0][256 + l * 4];
                float4 ha1 = *(const float4*)&h0_lds[b1][l * 4];
                float4 hb1 = *(const float4*)&h0_lds[b1][256 + l * 4];
                float2 xv0 = *(const float2*)&x_lds[b0][l * 2];
                float2 xv1 = *(const float2*)&x_lds[b1][l * 2];
                #pragma unroll
                for (int g = 0; g < 4; ++g) {
                    const size_t r = (size_t)g * HD + us;   // wave-uniform row
                    float4 wa = *(const float4*)(Whh0 + r * HD +       l * 4);
                    float4 wb = *(const float4*)(Whh0 + r * HD + 256 + l * 4);
                    float2 wx = *(const float2*)(Wih0 + r * IN + l * 2);
                    A[g * 16 + b0] += dot4(wa, ha0) + dot4(wb, hb0)
                                    + wx.x * xv0.x + wx.y * xv0.y;
                    A[g * 16 + b1] += dot4(wa, ha1) + dot4(wb, hb1)
                                    + wx.x * xv1.x + wx.y * xv1.y;
                }
            }
            r0 = wave_reduce64(A, l) + bias0;
        }
        // ---- layer1: batch-PAIR loop — each weight load feeds 2 batches ----
        if (s >= 1) {
            float A[64];
            #pragma unroll
            for (int j = 0; j < 64; ++j) A[j] = 0.0f;
            #pragma unroll
            for (int bp = 0; bp < BGB / 2; ++bp) {
                const int b0 = bp * 2, b1 = bp * 2 + 1;
                float4 ha0 = *(const float4*)&h0_lds[b0][l * 4];
                float4 hb0 = *(const float4*)&h0_lds[b0][256 + l * 4];
                float4 qa0 = *(const float4*)&h2_lds[b0][l * 4];
                float4 qb0 = *(const float4*)&h2_lds[b0][256 + l * 4];
                float4 ha1 = *(const float4*)&h0_lds[b1][l * 4];
                float4 hb1 = *(const float4*)&h0_lds[b1][256 + l * 4];
                float4 qa1 = *(const float4*)&h2_lds[b1][l * 4];
                float4 qb1 = *(const float4*)&h2_lds[b1][256 + l * 4];
                #pragma unroll
                for (int g = 0; g < 4; ++g) {
                    const size_t r = (size_t)g * HD + us;   // wave-uniform row
                    float4 wi0 = *(const float4*)(Wih1 + r * HD +       l * 4);
                    float4 wi1 = *(const float4*)(Wih1 + r * HD + 256 + l * 4);
                    float4 wh0 = *(const float4*)(Whh1 + r * HD +       l * 4);
                    float4 wh1 = *(const float4*)(Whh1 + r * HD + 256 + l * 4);
                    A[g * 16 + b0] += dot4(wi0, ha0) + dot4(wi1, hb0)
                                    + dot4(wh0, qa0) + dot4(wh1, qb0);
                    A[g * 16 + b1] += dot4(wi0, ha1) + dot4(wi1, hb1)
                                    + dot4(wh0, qa1) + dot4(wh1, qb1);
                }
            }
            r1 = wave_reduce64(A, l) + bias1;
        }

        // ---- gather gates to lanes 0..15 (shfl by ALL lanes), update state ----
        float gi0 = __shfl(r0, bl,      64);
        float gf0 = __shfl(r0, bl + 16, 64);
        float gc0 = __shfl(r0, bl + 32, 64);
        float go0 = __shfl(r0, bl + 48, 64);
        float gi1 = __shfl(r1, bl,      64);
        float gf1 = __shfl(r1, bl + 16, 64);
        float gc1 = __shfl(r1, bl + 32, 64);
        float go1 = __shfl(r1, bl + 48, 64);
        if (l < 16) {
            if (s < TT) {
                float cn = sigf(gf0) * c0r + sigf(gi0) * tanhf(gc0);
                c0r = cn;
                store_coh(h0T + cur * HD * NB + (size_t)us * NB + bg16 + bl,
                          sigf(go0) * tanhf(cn));
            }
            if (s >= 1) {
                float cn = sigf(gf1) * c2r + sigf(gi1) * tanhf(gc1);
                c2r = cn;
                store_coh(h2T + (cur ^ 1) * HD * NB + (size_t)us * NB + bg16 + bl,
                          sigf(go1) * tanhf(cn));   // h2_{s-1}
            }
        }

        // ---- arrive: barrier drains ALL waves' h stores (vmcnt0 each), then
        //      one independent slot store (no RMW convoy) ----
        __syncthreads();
        if (tid == 0) store_coh_int(gslots + rb, s + 1);
    }

    // ---------------- FC tail: one block per batch group ----------------
    if (rb != 0) return;
    {
        if (tid < 64) {
            const int* myslot = gslots + l;
            int spins = 0;
            while (!__all(load_coh_int(myslot) >= TT + 1)) {
                __builtin_amdgcn_s_sleep(2);
                if (++spins > (1 << 18)) break;
            }
        }
        __syncthreads();

        // h2[TT-1] lives in buffer (TT-1)&1 = 1  (coherent reads)
        const float* hsrc = h2T + 1 * HD * NB + (size_t)tid * NB + bg16;
        float4 q0, q1, q2, q3;
        load_coh16(hsrc, q0, q1, q2, q3);
        wait_vm0();
        h2_lds[ 0][tid]=q0.x; h2_lds[ 1][tid]=q0.y; h2_lds[ 2][tid]=q0.z; h2_lds[ 3][tid]=q0.w;
        h2_lds[ 4][tid]=q1.x; h2_lds[ 5][tid]=q1.y; h2_lds[ 6][tid]=q1.z; h2_lds[ 7][tid]=q1.w;
        h2_lds[ 8][tid]=q2.x; h2_lds[ 9][tid]=q2.y; h2_lds[10][tid]=q2.z; h2_lds[11][tid]=q2.w;
        h2_lds[12][tid]=q3.x; h2_lds[13][tid]=q3.y; h2_lds[14][tid]=q3.z; h2_lds[15][tid]=q3.w;
        __syncthreads();

        const int bb = tid >> 5, oo = tid & 31;
        if (oo < 24) {
            float acc = fcb[oo];
            const float4* hrow = (const float4*)&h2_lds[bb][0];
            const float4* wrow = (const float4*)(fcW + (size_t)oo * HD);
            #pragma unroll 8
            for (int q = 0; q < HD / 4; ++q) acc += dot4(hrow[q], wrow[q]);
            out[(size_t)(bg16 + bb) * 24 + oo] = acc;
        }
    }
}

extern "C" void kernel_launch(void* const* d_in, const int* in_sizes, int n_in,
                              void* d_out, int out_size, void* d_ws, size_t ws_size,
                              hipStream_t stream)
{
    const float* x    = (const float*)d_in[0];
    const float* Wih0 = (const float*)d_in[1];
    const float* Whh0 = (const float*)d_in[2];
    const float* bih0 = (const float*)d_in[3];
    const float* bhh0 = (const float*)d_in[4];
    const float* Wih1 = (const float*)d_in[5];
    const float* Whh1 = (const float*)d_in[6];
    const float* bih1 = (const float*)d_in[7];
    const float* bhh1 = (const float*)d_in[8];
    const float* fcW  = (const float*)d_in[9];
    const float* fcb  = (const float*)d_in[10];

    // zero h ping-pong buffers + flag slots every call (graph-capture-safe)
    hipMemsetAsync(d_ws, 0, (size_t)(4 * HD * NB) * sizeof(float) + 1024, stream);

    lstm_persist<<<dim3(BGN * RBN), dim3(512), 0, stream>>>(
        x, Wih0, Whh0, bih0, bhh0, Wih1, Whh1, bih1, bhh1, fcW, fcb,
        (float*)d_ws, (float*)d_out);
}